// Round 1
// baseline (267.329 us; speedup 1.0000x reference)
//
#include <hip/hip_runtime.h>
#include <math.h>

#define BIGV 1.0e8f
#define PLANE (512 * 512)            // 262144
#define NTOT  (8 * PLANE)            // 2097152
#define NSPATIAL PLANE               // 262144 spatial positions (axis1 == 1)

// ---------------------------------------------------------------------------
// Pass 1: 1-D squared DT along axis 3 (contiguous, length 512), binary input.
// d[i] = (distance to nearest nonzero y in the line)^2, or BIG if line empty.
// Early-exit outward scan: first hit at radius r is optimal (binary input).
// ---------------------------------------------------------------------------
__global__ __launch_bounds__(256) void dt_axis3(const int* __restrict__ y,
                                                float* __restrict__ g1) {
    int e = blockIdx.x * 256 + threadIdx.x;          // e in [0, NTOT)
    int i = e & 511;
    const int* yl = y + (e - i);                     // line base
    float m = yl[i] ? 0.0f : BIGV;
    if (m > 0.0f) {
        for (int r = 1; r < 512; ++r) {
            int lo = i - r, hi = i + r;
            bool hit = false;
            if (lo >= 0 && yl[lo]) hit = true;
            if (hi < 512 && yl[hi]) hit = true;
            if (hit) { m = (float)(r * r); break; }
            if (lo < 0 && hi >= 512) break;          // line exhausted -> BIG
        }
    }
    g1[e] = m;
}

// ---------------------------------------------------------------------------
// Pass 2: 1-D squared DT along axis 2 (stride 512 within a plane), general
// fp32 input. Exact early termination: stop when r^2 >= current min.
// Lanes vary along contiguous axis 3 -> coalesced row loads at each radius.
// ---------------------------------------------------------------------------
__global__ __launch_bounds__(256) void dt_axis2(const float* __restrict__ g1,
                                                float* __restrict__ g2) {
    int e = blockIdx.x * 256 + threadIdx.x;
    int b   = e >> 18;                                // plane index (batch)
    int rem = e & (PLANE - 1);
    int i2  = rem >> 9;                               // row (axis 2)
    int i3  = rem & 511;                              // col (axis 3)
    const float* col = g1 + b * PLANE + i3;           // element j at col[j<<9]
    float m = col[i2 << 9];
    for (int r = 1; r < 512; ++r) {
        float r2 = (float)(r * r);
        if (r2 >= m) break;
        int lo = i2 - r, hi = i2 + r;
        if (lo >= 0)  m = fminf(m, col[lo << 9] + r2);
        if (hi < 512) m = fminf(m, col[hi << 9] + r2);
        if (lo < 0 && hi >= 512) break;
    }
    g2[e] = m;
}

// ---------------------------------------------------------------------------
// Pass 3 (fused): 1-D squared DT along axis 0 (length 8, brute 8x8) +
// sqrt + sigmoid(x)*d + deterministic block partial sums (double).
// ---------------------------------------------------------------------------
__device__ inline double wave_reduce_d(double v) {
    #pragma unroll
    for (int off = 32; off > 0; off >>= 1) v += __shfl_down(v, off, 64);
    return v;
}

__global__ __launch_bounds__(256) void axis0_epilogue(const float* __restrict__ g2,
                                                      const float* __restrict__ x,
                                                      double* __restrict__ partials) {
    int s = blockIdx.x * 256 + threadIdx.x;           // spatial index [0, PLANE)
    float v[8];
    #pragma unroll
    for (int b = 0; b < 8; ++b) v[b] = g2[b * PLANE + s];

    double acc = 0.0;
    #pragma unroll
    for (int b = 0; b < 8; ++b) {
        float m = BIGV;
        #pragma unroll
        for (int bp = 0; bp < 8; ++bp) {
            float db = (float)((b - bp) * (b - bp));  // compile-time const
            m = fminf(m, v[bp] + db);
        }
        float xv  = x[b * PLANE + s];
        float sig = 1.0f / (1.0f + expf(-xv));
        acc += (double)(sig * sqrtf(m));
    }

    // block reduce (4 waves of 64)
    __shared__ double lds[4];
    double w = wave_reduce_d(acc);
    int lane = threadIdx.x & 63;
    int wid  = threadIdx.x >> 6;
    if (lane == 0) lds[wid] = w;
    __syncthreads();
    if (wid == 0) {
        double t = (lane < 4) ? lds[lane] : 0.0;
        #pragma unroll
        for (int off = 2; off > 0; off >>= 1) t += __shfl_down(t, off, 64);
        if (lane == 0) partials[blockIdx.x] = t;
    }
}

__global__ __launch_bounds__(256) void finalize(const double* __restrict__ partials,
                                                float* __restrict__ out) {
    double a = 0.0;
    for (int i = threadIdx.x; i < 1024; i += 256) a += partials[i];
    __shared__ double lds[4];
    double w = wave_reduce_d(a);
    int lane = threadIdx.x & 63;
    int wid  = threadIdx.x >> 6;
    if (lane == 0) lds[wid] = w;
    __syncthreads();
    if (threadIdx.x == 0) {
        double total = lds[0] + lds[1] + lds[2] + lds[3];
        out[0] = (float)(total / (double)NTOT);
    }
}

// ---------------------------------------------------------------------------
extern "C" void kernel_launch(void* const* d_in, const int* in_sizes, int n_in,
                              void* d_out, int out_size, void* d_ws, size_t ws_size,
                              hipStream_t stream) {
    const float* x = (const float*)d_in[0];
    const int*   y = (const int*)d_in[1];
    float* out = (float*)d_out;

    float*  g1       = (float*)d_ws;                       // 8 MB
    float*  g2       = g1 + NTOT;                          // 8 MB
    double* partials = (double*)(g2 + NTOT);               // 8 KB (1024 doubles)

    dt_axis3<<<NTOT / 256, 256, 0, stream>>>(y, g1);
    dt_axis2<<<NTOT / 256, 256, 0, stream>>>(g1, g2);
    axis0_epilogue<<<NSPATIAL / 256, 256, 0, stream>>>(g2, x, partials);
    finalize<<<1, 256, 0, stream>>>(partials, out);
}

// Round 2
// 104.986 us; speedup vs baseline: 2.5463x; 2.5463x over previous
//
#include <hip/hip_runtime.h>
#include <math.h>

#define BIGV 1.0e8f
#define PLANE (512 * 512)            // 262144
#define NTOT  (8 * PLANE)            // 2097152
#define NSPATIAL PLANE               // 262144 spatial positions (axis1 == 1)

// ---------------------------------------------------------------------------
// Pass 1: 1-D squared DT along axis 3 (contiguous, length 512), binary input.
// One 512-thread block per line. Build the line's 512-bit occupancy mask via
// wave ballots (8 x 64-bit words in LDS), then each element finds its nearest
// set bit with clz/ctz word probes (<=8 words per direction, unrolled).
// ---------------------------------------------------------------------------
__global__ __launch_bounds__(512) void dt_axis3(const int* __restrict__ y,
                                                float* __restrict__ g1) {
    __shared__ unsigned long long words[8];
    int i = threadIdx.x;                              // position in line [0,512)
    int e = blockIdx.x * 512 + i;
    int set = (y[e] != 0) ? 1 : 0;
    unsigned long long bal = __ballot(set);
    int wid  = i >> 6;
    int lane = i & 63;
    if (lane == 0) words[wid] = bal;
    __syncthreads();

    int k = wid, b = lane;
    int dr = 1 << 30;
    {
        unsigned long long m0 = words[k] & (~0ull << b);   // bits >= i in word k
        if (m0) {
            dr = (__ffsll((long long)m0) - 1) - b;
        } else {
            #pragma unroll
            for (int k2 = 0; k2 < 8; ++k2) {
                if (k2 > k && dr == (1 << 30) && words[k2]) {
                    dr = (k2 << 6) + (__ffsll((long long)words[k2]) - 1) - i;
                }
            }
        }
    }
    int dl = 1 << 30;
    {
        unsigned long long m0 = words[k] & (~0ull >> (63 - b)); // bits <= i
        if (m0) {
            dl = b - (63 - __clzll((long long)m0));
        } else {
            #pragma unroll
            for (int k2 = 7; k2 >= 0; --k2) {
                if (k2 < k && dl == (1 << 30) && words[k2]) {
                    dl = i - ((k2 << 6) + 63 - __clzll((long long)words[k2]));
                }
            }
        }
    }
    int d = min(dl, dr);
    g1[e] = (d > 511) ? BIGV : (float)(d * d);
}

// ---------------------------------------------------------------------------
// Pass 2: 1-D squared DT along axis 2 (stride 512 within a plane), general
// fp32 input. Exact early termination: stop when r^2 >= current min.
// Lanes vary along contiguous axis 3 -> coalesced row loads at each radius.
// ---------------------------------------------------------------------------
__global__ __launch_bounds__(256) void dt_axis2(const float* __restrict__ g1,
                                                float* __restrict__ g2) {
    int e = blockIdx.x * 256 + threadIdx.x;
    int b   = e >> 18;                                // plane index (batch)
    int rem = e & (PLANE - 1);
    int i2  = rem >> 9;                               // row (axis 2)
    int i3  = rem & 511;                              // col (axis 3)
    const float* col = g1 + b * PLANE + i3;           // element j at col[j<<9]
    float m = col[i2 << 9];
    for (int r = 1; r < 512; ++r) {
        float r2 = (float)(r * r);
        if (r2 >= m) break;
        int lo = i2 - r, hi = i2 + r;
        if (lo >= 0)  m = fminf(m, col[lo << 9] + r2);
        if (hi < 512) m = fminf(m, col[hi << 9] + r2);
        if (lo < 0 && hi >= 512) break;
    }
    g2[e] = m;
}

// ---------------------------------------------------------------------------
// Pass 3 (fused): 1-D squared DT along axis 0 (length 8, brute 8x8) +
// sqrt + sigmoid(x)*d + deterministic block partial sums (double).
// ---------------------------------------------------------------------------
__device__ inline double wave_reduce_d(double v) {
    #pragma unroll
    for (int off = 32; off > 0; off >>= 1) v += __shfl_down(v, off, 64);
    return v;
}

__global__ __launch_bounds__(256) void axis0_epilogue(const float* __restrict__ g2,
                                                      const float* __restrict__ x,
                                                      double* __restrict__ partials) {
    int s = blockIdx.x * 256 + threadIdx.x;           // spatial index [0, PLANE)
    float v[8];
    #pragma unroll
    for (int b = 0; b < 8; ++b) v[b] = g2[b * PLANE + s];

    double acc = 0.0;
    #pragma unroll
    for (int b = 0; b < 8; ++b) {
        float m = BIGV;
        #pragma unroll
        for (int bp = 0; bp < 8; ++bp) {
            float db = (float)((b - bp) * (b - bp));  // compile-time const
            m = fminf(m, v[bp] + db);
        }
        float xv  = x[b * PLANE + s];
        float sig = 1.0f / (1.0f + expf(-xv));
        acc += (double)(sig * sqrtf(m));
    }

    // block reduce (4 waves of 64)
    __shared__ double lds[4];
    double w = wave_reduce_d(acc);
    int lane = threadIdx.x & 63;
    int wid  = threadIdx.x >> 6;
    if (lane == 0) lds[wid] = w;
    __syncthreads();
    if (wid == 0) {
        double t = (lane < 4) ? lds[lane] : 0.0;
        #pragma unroll
        for (int off = 2; off > 0; off >>= 1) t += __shfl_down(t, off, 64);
        if (lane == 0) partials[blockIdx.x] = t;
    }
}

__global__ __launch_bounds__(256) void finalize(const double* __restrict__ partials,
                                                float* __restrict__ out) {
    double a = 0.0;
    for (int i = threadIdx.x; i < 1024; i += 256) a += partials[i];
    __shared__ double lds[4];
    double w = wave_reduce_d(a);
    int lane = threadIdx.x & 63;
    int wid  = threadIdx.x >> 6;
    if (lane == 0) lds[wid] = w;
    __syncthreads();
    if (threadIdx.x == 0) {
        double total = lds[0] + lds[1] + lds[2] + lds[3];
        out[0] = (float)(total / (double)NTOT);
    }
}

// ---------------------------------------------------------------------------
extern "C" void kernel_launch(void* const* d_in, const int* in_sizes, int n_in,
                              void* d_out, int out_size, void* d_ws, size_t ws_size,
                              hipStream_t stream) {
    const float* x = (const float*)d_in[0];
    const int*   y = (const int*)d_in[1];
    float* out = (float*)d_out;

    float*  g1       = (float*)d_ws;                       // 8 MB
    float*  g2       = g1 + NTOT;                          // 8 MB
    double* partials = (double*)(g2 + NTOT);               // 8 KB (1024 doubles)

    dt_axis3<<<NTOT / 512, 512, 0, stream>>>(y, g1);
    dt_axis2<<<NTOT / 256, 256, 0, stream>>>(g1, g2);
    axis0_epilogue<<<NSPATIAL / 256, 256, 0, stream>>>(g2, x, partials);
    finalize<<<1, 256, 0, stream>>>(partials, out);
}